// Round 1
// baseline (9635.883 us; speedup 1.0000x reference)
//
#include <hip/hip_runtime.h>
#include <math.h>

#define TT 256
#define BB 128
#define II 512
#define HH 1024
#define KK 1536   // II + HH
#define NCLS 1000

typedef __bf16 bf16;
typedef bf16 bf16x8 __attribute__((ext_vector_type(8)));
typedef float f32x4 __attribute__((ext_vector_type(4)));

// ---------------- init h0/c0 ----------------
__global__ void init_state(bf16* __restrict__ h0, float* __restrict__ c) {
    int idx = blockIdx.x * 256 + threadIdx.x;
    if (idx < BB * HH) { h0[idx] = (bf16)0.0f; c[idx] = 0.0f; }
}

// ---------------- pack weights: Wt[n][k], n = g*1024+h (4096 rows), k in [0,1536) ----------------
// k<512: W_{g}x[k][h]; k>=512: g<3 ? W_{g}h[k-512][h] : 0
__global__ void pack_w(const float* __restrict__ Wfx, const float* __restrict__ Wfh,
                       const float* __restrict__ Wix, const float* __restrict__ Wih,
                       const float* __restrict__ Wox, const float* __restrict__ Woh,
                       const float* __restrict__ Wcx, bf16* __restrict__ Wt) {
    int bt = blockIdx.x;              // 64 n-tiles x 24 k-tiles
    int nt = bt / 24, kt = bt % 24;
    int n0 = nt * 64, k0 = kt * 64;
    int g = n0 >> 10, hn0 = n0 & 1023;
    const float* src = nullptr;
    int kbase = 0;
    if (k0 < II) {
        src = (g == 0) ? Wfx : (g == 1) ? Wix : (g == 2) ? Wox : Wcx;
        kbase = k0;
    } else if (g < 3) {
        src = (g == 0) ? Wfh : (g == 1) ? Wih : Woh;
        kbase = k0 - II;
    }
    __shared__ bf16 tile[64][65];
    int tid = threadIdx.x;
    for (int i = tid; i < 64 * 64; i += 256) {
        int kr = i >> 6, nc = i & 63;
        float v = src ? src[(size_t)(kbase + kr) * HH + hn0 + nc] : 0.0f;
        tile[kr][nc] = (bf16)v;
    }
    __syncthreads();
    for (int i = tid; i < 64 * 64; i += 256) {
        int nc = i >> 6, kr = i & 63;
        Wt[(size_t)(n0 + nc) * KK + k0 + kr] = tile[kr][nc];
    }
}

__global__ void pack_bias(const float* __restrict__ bf_, const float* __restrict__ bi_,
                          const float* __restrict__ bo_, const float* __restrict__ bc_,
                          float* __restrict__ bias) {
    int i = blockIdx.x * 256 + threadIdx.x;
    if (i < 4 * HH) {
        int g = i >> 10, hn = i & 1023;
        const float* b = (g == 0) ? bf_ : (g == 1) ? bi_ : (g == 2) ? bo_ : bc_;
        bias[i] = b[hn];
    }
}

// ---------------- fused recurrent step ----------------
// grid = 64 (H/16), block = 256 (4 waves). Block computes gates f,i,o,c for
// all 128 batch rows at h-cols [n0, n0+16). A = [x_t | h_prev] bf16, K=1536.
__global__ __launch_bounds__(256) void lstm_step(
    const float* __restrict__ x, const bf16* __restrict__ Wt,
    const float* __restrict__ bias, const bf16* __restrict__ h_in,
    bf16* __restrict__ h_out, float* __restrict__ c, int t) {
    const int tid  = threadIdx.x;
    const int wave = tid >> 6, lane = tid & 63;
    const int n0   = blockIdx.x * 16;

    __shared__ __align__(16) bf16 Alds[128][40];  // [b][k] padded (80B stride)
    __shared__ __align__(16) bf16 Wlds[64][40];   // [col][k] padded, col = g*16+j

    f32x4 acc[2][4] = {};

    // staging assignment
    const int arow = tid >> 1, akc = (tid & 1) * 16;   // A: 2 thr/row, 16 elems each
    const int wcol = tid >> 2, wko = (tid & 3) * 8;    // W: 4 thr/col, 8 elems each
    const int wg   = wcol >> 4;                         // gate of this thread's W col (== wave)
    const size_t wrow_off = (size_t)(wg * HH + n0 + (wcol & 15)) * KK;

    bf16x8 a0, a1, wv;
    auto loadA = [&](int k0) {
        int kg = k0 + akc;
        if (k0 < II) {  // x part (fp32 -> bf16)
            const float* s = x + ((size_t)arow * TT + t) * II + kg;
            float4 f0 = *(const float4*)(s);
            float4 f1 = *(const float4*)(s + 4);
            float4 f2 = *(const float4*)(s + 8);
            float4 f3 = *(const float4*)(s + 12);
            bf16x8 u, v;
            u[0]=(bf16)f0.x; u[1]=(bf16)f0.y; u[2]=(bf16)f0.z; u[3]=(bf16)f0.w;
            u[4]=(bf16)f1.x; u[5]=(bf16)f1.y; u[6]=(bf16)f1.z; u[7]=(bf16)f1.w;
            v[0]=(bf16)f2.x; v[1]=(bf16)f2.y; v[2]=(bf16)f2.z; v[3]=(bf16)f2.w;
            v[4]=(bf16)f3.x; v[5]=(bf16)f3.y; v[6]=(bf16)f3.z; v[7]=(bf16)f3.w;
            a0 = u; a1 = v;
        } else {        // h part (already bf16)
            const bf16* s = h_in + (size_t)arow * HH + (kg - II);
            a0 = *(const bf16x8*)(s);
            a1 = *(const bf16x8*)(s + 8);
        }
    };
    auto loadW = [&](int k0) {
        if (!(wg == 3 && k0 >= II))   // gate c has no h-part (zeros) — skip
            wv = *(const bf16x8*)(Wt + wrow_off + k0 + wko);
    };

    loadA(0); loadW(0);
    #pragma unroll 1
    for (int kk = 0; kk < KK / 32; ++kk) {
        const int k0 = kk * 32;
        *(bf16x8*)(&Alds[arow][akc])     = a0;
        *(bf16x8*)(&Alds[arow][akc + 8]) = a1;
        if (!(wg == 3 && k0 >= II)) *(bf16x8*)(&Wlds[wcol][wko]) = wv;
        __syncthreads();
        if (kk + 1 < KK / 32) { loadA(k0 + 32); loadW(k0 + 32); }
        const int lr = lane & 15, lk = (lane >> 4) * 8;
        bf16x8 af0 = *(const bf16x8*)(&Alds[wave * 32 + lr][lk]);
        bf16x8 af1 = *(const bf16x8*)(&Alds[wave * 32 + 16 + lr][lk]);
        #pragma unroll
        for (int g = 0; g < 4; ++g) {
            if (g == 3 && k0 >= II) continue;  // candidate gate: K=512 only
            bf16x8 bfr = *(const bf16x8*)(&Wlds[g * 16 + lr][lk]);
            acc[0][g] = __builtin_amdgcn_mfma_f32_16x16x32_bf16(af0, bfr, acc[0][g], 0, 0, 0);
            acc[1][g] = __builtin_amdgcn_mfma_f32_16x16x32_bf16(af1, bfr, acc[1][g], 0, 0, 0);
        }
        __syncthreads();
    }

    // epilogue: D lane mapping col=lane&15, row=(lane>>4)*4+reg  [m89-verified]
    const int lcol  = lane & 15;
    const int rbase = (lane >> 4) * 4;
    const int hcol  = n0 + lcol;
    const float bsf = bias[0 * HH + hcol];
    const float bsi = bias[1 * HH + hcol];
    const float bso = bias[2 * HH + hcol];
    const float bsc = bias[3 * HH + hcol];
    #pragma unroll
    for (int mi = 0; mi < 2; ++mi) {
        #pragma unroll
        for (int jr = 0; jr < 4; ++jr) {
            const int b = wave * 32 + mi * 16 + rbase + jr;
            const size_t off = (size_t)b * HH + hcol;
            float pf = acc[mi][0][jr] + bsf;
            float pi = acc[mi][1][jr] + bsi;
            float po = acc[mi][2][jr] + bso;
            float pc = acc[mi][3][jr] + bsc;
            float fg = 1.0f / (1.0f + expf(-pf));
            float ig = 1.0f / (1.0f + expf(-pi));
            float og = 1.0f / (1.0f + expf(-po));
            float cn = tanhf(pc) * ig + c[off] * fg;
            c[off] = cn;
            h_out[off] = (bf16)(tanhf(cn) * og);
        }
    }
}

// ---------------- head: logits = h @ W_ph + b_p ----------------
__global__ __launch_bounds__(256) void logits_kernel(
    const bf16* __restrict__ h, const float* __restrict__ Wp,
    const float* __restrict__ bp, float* __restrict__ out) {
    const int tid = threadIdx.x;
    const int r0  = blockIdx.x * 8;
    __shared__ float hs[8][HH];
    for (int i = tid; i < 8 * HH; i += 256)
        hs[i >> 10][i & 1023] = (float)h[(size_t)(r0 + (i >> 10)) * HH + (i & 1023)];
    __syncthreads();
    float acc[8][4] = {};
    for (int k = 0; k < HH; ++k) {
        float w[4];
        #pragma unroll
        for (int m = 0; m < 4; ++m) {
            int cc = tid + 256 * m;
            w[m] = (cc < NCLS) ? Wp[(size_t)k * NCLS + cc] : 0.0f;
        }
        #pragma unroll
        for (int r = 0; r < 8; ++r) {
            float hv = hs[r][k];
            #pragma unroll
            for (int m = 0; m < 4; ++m) acc[r][m] += hv * w[m];
        }
    }
    #pragma unroll
    for (int r = 0; r < 8; ++r) {
        #pragma unroll
        for (int m = 0; m < 4; ++m) {
            int cc = tid + 256 * m;
            if (cc < NCLS) out[(size_t)(r0 + r) * NCLS + cc] = acc[r][m] + bp[cc];
        }
    }
}

// ---------------- softmax over C=1000 per row ----------------
__global__ __launch_bounds__(256) void softmax_kernel(const float* __restrict__ logits,
                                                      float* __restrict__ out) {
    const int b = blockIdx.x, tid = threadIdx.x;
    __shared__ float red[256];
    float v[4];
    float mx = -1e30f;
    #pragma unroll
    for (int m = 0; m < 4; ++m) {
        int cc = tid + 256 * m;
        v[m] = (cc < NCLS) ? logits[(size_t)b * NCLS + cc] : -1e30f;
        mx = fmaxf(mx, v[m]);
    }
    red[tid] = mx; __syncthreads();
    for (int s = 128; s > 0; s >>= 1) {
        if (tid < s) red[tid] = fmaxf(red[tid], red[tid + s]);
        __syncthreads();
    }
    mx = red[0]; __syncthreads();
    float sum = 0.0f;
    #pragma unroll
    for (int m = 0; m < 4; ++m) {
        int cc = tid + 256 * m;
        if (cc < NCLS) { v[m] = expf(v[m] - mx); sum += v[m]; }
    }
    red[tid] = sum; __syncthreads();
    for (int s = 128; s > 0; s >>= 1) {
        if (tid < s) red[tid] += red[tid + s];
        __syncthreads();
    }
    float inv = 1.0f / red[0];
    #pragma unroll
    for (int m = 0; m < 4; ++m) {
        int cc = tid + 256 * m;
        if (cc < NCLS) out[(size_t)b * NCLS + cc] = v[m] * inv;
    }
}

extern "C" void kernel_launch(void* const* d_in, const int* in_sizes, int n_in,
                              void* d_out, int out_size, void* d_ws, size_t ws_size,
                              hipStream_t stream) {
    const float* x   = (const float*)d_in[0];
    const float* Wfx = (const float*)d_in[1];
    const float* Wfh = (const float*)d_in[2];
    const float* bf_ = (const float*)d_in[3];
    const float* Wix = (const float*)d_in[4];
    const float* Wih = (const float*)d_in[5];
    const float* bi_ = (const float*)d_in[6];
    const float* Wox = (const float*)d_in[7];
    const float* Woh = (const float*)d_in[8];
    const float* bo_ = (const float*)d_in[9];
    const float* Wcx = (const float*)d_in[10];
    const float* bc_ = (const float*)d_in[11];
    const float* Wp  = (const float*)d_in[12];
    const float* bp  = (const float*)d_in[13];

    char* ws = (char*)d_ws;
    bf16*  Wt   = (bf16*)(ws);                 // 4096*1536*2 = 12,582,912 B
    float* bias = (float*)(ws + 12582912);     // 16,384 B
    bf16*  hb0  = (bf16*)(ws + 12599296);      // 262,144 B
    bf16*  hb1  = (bf16*)(ws + 12861440);      // 262,144 B
    float* cbuf = (float*)(ws + 13123584);     // 524,288 B
    float* lg   = (float*)(ws + 13647872);     // 512,000 B  (total ~14.2 MB)

    init_state<<<(BB * HH + 255) / 256, 256, 0, stream>>>(hb0, cbuf);
    pack_w<<<64 * 24, 256, 0, stream>>>(Wfx, Wfh, Wix, Wih, Wox, Woh, Wcx, Wt);
    pack_bias<<<16, 256, 0, stream>>>(bf_, bi_, bo_, bc_, bias);

    bf16* hping[2] = {hb0, hb1};
    for (int t = 0; t < TT; ++t) {
        lstm_step<<<HH / 16, 256, 0, stream>>>(x, Wt, bias, hping[t & 1],
                                               hping[(t + 1) & 1], cbuf, t);
    }
    // T=256 even -> final h is in hb0
    logits_kernel<<<BB / 8, 256, 0, stream>>>(hb0, Wp, bp, lg);
    softmax_kernel<<<BB, 256, 0, stream>>>(lg, (float*)d_out);
}

// Round 2
// 6674.722 us; speedup vs baseline: 1.4436x; 1.4436x over previous
//
#include <hip/hip_runtime.h>
#include <math.h>

#define TT 256
#define BB 128
#define II 512
#define HH 1024
#define NCLS 1000
#define NBLK 128          // persistent blocks
#define CPB 8             // h-cols per block

typedef __bf16 bf16;
typedef bf16 bf16x8 __attribute__((ext_vector_type(8)));
typedef float f32x4 __attribute__((ext_vector_type(4)));

// ---------------- ws layout (bytes) ----------------
#define OFF_WHPK   0u            // 128*24*1024*2 = 6,291,456
#define OFF_WXPK   6291456u      // 128*32*512*2  = 4,194,304
#define OFF_BIAS   10485760u     // 16,384
#define OFF_HB0    10502144u     // 262,144
#define OFF_HB1    10764288u     // 262,144
#define OFF_FLAGS  11026432u     // 4,096
#define OFF_LG     11030528u     // 512,000
#define OFF_XB     11542528u     // 33,554,432 (optional)
#define WS_BIG     45096960u

// ---------------- init: zero h0 and flags ----------------
__global__ void init_state(bf16* __restrict__ h0, int* __restrict__ flags) {
    int idx = blockIdx.x * 256 + threadIdx.x;
    if (idx < BB * HH) h0[idx] = (bf16)0.0f;
    if (idx < NBLK) flags[idx] = 0;
}

// ---------------- pack W_h -> WhPK[bid][g*8+c8][k], g in {f,i,o} ----------------
__global__ void pack_wh(const float* __restrict__ Wfh, const float* __restrict__ Wih,
                        const float* __restrict__ Woh, bf16* __restrict__ WhPK) {
    int blk = blockIdx.x;                 // 3 * 16 * 16
    int g = blk / 256, rem = blk % 256;
    int ht = rem / 16, kt = rem % 16;
    const float* src = (g == 0) ? Wfh : (g == 1) ? Wih : Woh;
    __shared__ bf16 tile[64][72];
    int tid = threadIdx.x;
    for (int i = tid; i < 4096; i += 256) {
        int kr = i >> 6, hc = i & 63;
        tile[kr][hc] = (bf16)src[(size_t)(kt * 64 + kr) * HH + ht * 64 + hc];
    }
    __syncthreads();
    for (int i = tid; i < 4096; i += 256) {
        int hc = i >> 6, kr = i & 63;
        int h = ht * 64 + hc, bid = h >> 3, c8 = h & 7;
        WhPK[((size_t)bid * 24 + g * 8 + c8) * 1024 + kt * 64 + kr] = tile[kr][hc];
    }
}

// ---------------- pack W_x -> WxPK[bid][g*8+c8][k], g in {f,i,o,c} ----------------
__global__ void pack_wx(const float* __restrict__ Wfx, const float* __restrict__ Wix,
                        const float* __restrict__ Wox, const float* __restrict__ Wcx,
                        bf16* __restrict__ WxPK) {
    int blk = blockIdx.x;                 // 4 * 16 * 8
    int g = blk / 128, rem = blk % 128;
    int ht = rem / 8, kt = rem % 8;
    const float* src = (g == 0) ? Wfx : (g == 1) ? Wix : (g == 2) ? Wox : Wcx;
    __shared__ bf16 tile[64][72];
    int tid = threadIdx.x;
    for (int i = tid; i < 4096; i += 256) {
        int kr = i >> 6, hc = i & 63;
        tile[kr][hc] = (bf16)src[(size_t)(kt * 64 + kr) * HH + ht * 64 + hc];
    }
    __syncthreads();
    for (int i = tid; i < 4096; i += 256) {
        int hc = i >> 6, kr = i & 63;
        int h = ht * 64 + hc, bid = h >> 3, c8 = h & 7;
        WxPK[((size_t)bid * 32 + g * 8 + c8) * 512 + kt * 64 + kr] = tile[kr][hc];
    }
}

__global__ void pack_bias(const float* __restrict__ bf_, const float* __restrict__ bi_,
                          const float* __restrict__ bo_, const float* __restrict__ bc_,
                          float* __restrict__ bias) {
    int i = blockIdx.x * 256 + threadIdx.x;
    if (i < 4 * HH) {
        int g = i >> 10, hn = i & 1023;
        const float* b = (g == 0) ? bf_ : (g == 1) ? bi_ : (g == 2) ? bo_ : bc_;
        bias[i] = b[hn];
    }
}

// ---------------- x -> bf16 (optional fast path) ----------------
__global__ void conv_x(const float* __restrict__ x, bf16* __restrict__ xb) {
    size_t i = ((size_t)blockIdx.x * 256 + threadIdx.x) * 8;
    float4 f0 = *(const float4*)(x + i);
    float4 f1 = *(const float4*)(x + i + 4);
    bf16x8 v;
    v[0]=(bf16)f0.x; v[1]=(bf16)f0.y; v[2]=(bf16)f0.z; v[3]=(bf16)f0.w;
    v[4]=(bf16)f1.x; v[5]=(bf16)f1.y; v[6]=(bf16)f1.z; v[7]=(bf16)f1.w;
    *(bf16x8*)(xb + i) = v;
}

__device__ __forceinline__ float sigm(float x) {
    return 1.0f / (1.0f + __expf(-x));
}
__device__ __forceinline__ float tanh_f(float x) {
    float e = __expf(-2.0f * fabsf(x));       // <= 1, no overflow
    float t = (1.0f - e) / (1.0f + e);
    return copysignf(t, x);
}

// ---------------- persistent recurrent kernel ----------------
// 128 blocks x 256 threads. Block owns h-cols [bid*8, bid*8+8).
// LDS: WhL 32 rows x 1024 bf16 (64KB, XOR-swizzled); rows 0-7=f, 8-15=i, 16-23=o, 24-31=zero(c).
// Tiles: tau0 cols = {f x8, i x8}, tau1 cols = {o x8, c x8}.
template<bool XB>
__global__ __launch_bounds__(256) void lstm_persist(
    const float* __restrict__ xf, const bf16* __restrict__ xbb,
    const bf16* __restrict__ WhPK, const bf16* __restrict__ WxPK,
    const float* __restrict__ bias,
    bf16* __restrict__ hb0, bf16* __restrict__ hb1,
    int* __restrict__ flags) {
    extern __shared__ char lds[];
    const int tid = threadIdx.x, wave = tid >> 6, lane = tid & 63;
    const int bid = blockIdx.x, n0 = bid * CPB;

    // ---- stage Wh slice into LDS (swizzled), zero rows 24..31 ----
    for (int i = tid; i < 24 * 128; i += 256) {
        int r = i >> 7, k0 = (i & 127) * 8;
        bf16x8 v = *(const bf16x8*)(WhPK + ((size_t)bid * 24 + r) * 1024 + k0);
        int byte = (r * 2048 + k0 * 2) ^ ((r & 7) << 4);
        *(bf16x8*)(lds + byte) = v;
    }
    for (int i = tid; i < 8 * 128; i += 256) {
        int r = 24 + (i >> 7), k0 = (i & 127) * 8;
        int byte = (r * 2048 + k0 * 2) ^ ((r & 7) << 4);
        *(int4*)(lds + byte) = make_int4(0, 0, 0, 0);
    }
    __syncthreads();

    const int lr = lane & 15;            // A-row / B-col within tile
    const int lk = (lane >> 4) * 8;      // k offset within 32-chunk
    const int c16 = lr;
    const bool lo = (c16 < 8);
    const int hc = n0 + (c16 & 7);
    const float b0 = bias[(lo ? 0 : 1) * HH + hc];   // f or i
    const float b1 = bias[(lo ? 2 : 3) * HH + hc];   // o or c
    float creg[2][2] = {{0.f, 0.f}, {0.f, 0.f}};     // [m][j2], owner-fixed

    for (int t = 0; t < TT; ++t) {
        f32x4 acc[2][2] = {};            // [m][tau]

        // ---- x-part (K=512), no h dependency: hides sync latency ----
        #pragma unroll 4
        for (int kk = 0; kk < 16; ++kk) {
            const int k0 = kk * 32 + lk;
            bf16x8 a0, a1;
            if (XB) {
                a0 = *(const bf16x8*)(xbb + ((size_t)(wave * 32 + lr) * TT + t) * II + k0);
                a1 = *(const bf16x8*)(xbb + ((size_t)(wave * 32 + 16 + lr) * TT + t) * II + k0);
            } else {
                const float* s0 = xf + ((size_t)(wave * 32 + lr) * TT + t) * II + k0;
                const float* s1 = xf + ((size_t)(wave * 32 + 16 + lr) * TT + t) * II + k0;
                float4 f0 = *(const float4*)s0, f1 = *(const float4*)(s0 + 4);
                float4 g0 = *(const float4*)s1, g1 = *(const float4*)(s1 + 4);
                a0[0]=(bf16)f0.x; a0[1]=(bf16)f0.y; a0[2]=(bf16)f0.z; a0[3]=(bf16)f0.w;
                a0[4]=(bf16)f1.x; a0[5]=(bf16)f1.y; a0[6]=(bf16)f1.z; a0[7]=(bf16)f1.w;
                a1[0]=(bf16)g0.x; a1[1]=(bf16)g0.y; a1[2]=(bf16)g0.z; a1[3]=(bf16)g0.w;
                a1[4]=(bf16)g1.x; a1[5]=(bf16)g1.y; a1[6]=(bf16)g1.z; a1[7]=(bf16)g1.w;
            }
            #pragma unroll
            for (int tau = 0; tau < 2; ++tau) {
                const int r = tau * 16 + lr;
                bf16x8 b = *(const bf16x8*)(WxPK + ((size_t)bid * 32 + r) * 512 + k0);
                acc[0][tau] = __builtin_amdgcn_mfma_f32_16x16x32_bf16(a0, b, acc[0][tau], 0, 0, 0);
                acc[1][tau] = __builtin_amdgcn_mfma_f32_16x16x32_bf16(a1, b, acc[1][tau], 0, 0, 0);
            }
        }

        // ---- wait for h_t (all producers done with step t-1) ----
        if (wave == 0) {
            while (true) {
                int v0 = __hip_atomic_load(&flags[lane],      __ATOMIC_RELAXED, __HIP_MEMORY_SCOPE_AGENT);
                int v1 = __hip_atomic_load(&flags[lane + 64], __ATOMIC_RELAXED, __HIP_MEMORY_SCOPE_AGENT);
                if (__all((v0 >= t) && (v1 >= t))) break;
                __builtin_amdgcn_s_sleep(2);
            }
        }
        __syncthreads();
        __builtin_amdgcn_fence(__ATOMIC_ACQUIRE, "agent");

        // ---- h-part (K=1024) ----
        const bf16* hin = (t & 1) ? hb1 : hb0;
        #pragma unroll 4
        for (int kk = 0; kk < 32; ++kk) {
            const int k0 = kk * 32 + lk;
            bf16x8 a0 = *(const bf16x8*)(hin + (size_t)(wave * 32 + lr) * HH + k0);
            bf16x8 a1 = *(const bf16x8*)(hin + (size_t)(wave * 32 + 16 + lr) * HH + k0);
            #pragma unroll
            for (int tau = 0; tau < 2; ++tau) {
                const int r = tau * 16 + lr;
                bf16x8 b = *(const bf16x8*)(lds + ((r * 2048 + k0 * 2) ^ ((r & 7) << 4)));
                acc[0][tau] = __builtin_amdgcn_mfma_f32_16x16x32_bf16(a0, b, acc[0][tau], 0, 0, 0);
                acc[1][tau] = __builtin_amdgcn_mfma_f32_16x16x32_bf16(a1, b, acc[1][tau], 0, 0, 0);
            }
        }

        // ---- pointwise: exchange partner gates via shfl_xor(8), c in regs ----
        bf16* hout = (t & 1) ? hb0 : hb1;
        #pragma unroll
        for (int m = 0; m < 2; ++m) {
            float p0[4], p1[4];
            #pragma unroll
            for (int j = 0; j < 4; ++j) { p0[j] = acc[m][0][j] + b0; p1[j] = acc[m][1][j] + b1; }
            #pragma unroll
            for (int j2 = 0; j2 < 2; ++j2) {
                float send0 = lo ? p0[j2 + 2] : p0[j2];
                float recv0 = __shfl_xor(send0, 8);
                float send1 = lo ? p1[j2 + 2] : p1[j2];
                float recv1 = __shfl_xor(send1, 8);
                float pf = lo ? p0[j2] : recv0;
                float pi = lo ? recv0  : p0[j2 + 2];
                float po = lo ? p1[j2] : recv1;
                float pc = lo ? recv1  : p1[j2 + 2];
                float fg = sigm(pf), ig = sigm(pi), og = sigm(po);
                float cn = tanh_f(pc) * ig + creg[m][j2] * fg;
                creg[m][j2] = cn;
                const int jr = lo ? j2 : j2 + 2;
                const int brow = wave * 32 + m * 16 + (lane >> 4) * 4 + jr;
                hout[(size_t)brow * HH + hc] = (bf16)(tanh_f(cn) * og);
            }
        }
        __syncthreads();
        if (tid == 0)
            __hip_atomic_store(&flags[bid], t + 1, __ATOMIC_RELEASE, __HIP_MEMORY_SCOPE_AGENT);
    }
}

// ---------------- head: logits = h @ W_ph + b_p ----------------
__global__ __launch_bounds__(256) void logits_kernel(
    const bf16* __restrict__ h, const float* __restrict__ Wp,
    const float* __restrict__ bp, float* __restrict__ out) {
    const int tid = threadIdx.x;
    const int r0  = blockIdx.x * 8;
    __shared__ float hs[8][HH];
    for (int i = tid; i < 8 * HH; i += 256)
        hs[i >> 10][i & 1023] = (float)h[(size_t)(r0 + (i >> 10)) * HH + (i & 1023)];
    __syncthreads();
    float acc[8][4] = {};
    for (int k = 0; k < HH; ++k) {
        float w[4];
        #pragma unroll
        for (int m = 0; m < 4; ++m) {
            int cc = tid + 256 * m;
            w[m] = (cc < NCLS) ? Wp[(size_t)k * NCLS + cc] : 0.0f;
        }
        #pragma unroll
        for (int r = 0; r < 8; ++r) {
            float hv = hs[r][k];
            #pragma unroll
            for (int m = 0; m < 4; ++m) acc[r][m] += hv * w[m];
        }
    }
    #pragma unroll
    for (int r = 0; r < 8; ++r) {
        #pragma unroll
        for (int m = 0; m < 4; ++m) {
            int cc = tid + 256 * m;
            if (cc < NCLS) out[(size_t)(r0 + r) * NCLS + cc] = acc[r][m] + bp[cc];
        }
    }
}

// ---------------- softmax over C=1000 per row ----------------
__global__ __launch_bounds__(256) void softmax_kernel(const float* __restrict__ logits,
                                                      float* __restrict__ out) {
    const int b = blockIdx.x, tid = threadIdx.x;
    __shared__ float red[256];
    float v[4];
    float mx = -1e30f;
    #pragma unroll
    for (int m = 0; m < 4; ++m) {
        int cc = tid + 256 * m;
        v[m] = (cc < NCLS) ? logits[(size_t)b * NCLS + cc] : -1e30f;
        mx = fmaxf(mx, v[m]);
    }
    red[tid] = mx; __syncthreads();
    for (int s = 128; s > 0; s >>= 1) {
        if (tid < s) red[tid] = fmaxf(red[tid], red[tid + s]);
        __syncthreads();
    }
    mx = red[0]; __syncthreads();
    float sum = 0.0f;
    #pragma unroll
    for (int m = 0; m < 4; ++m) {
        int cc = tid + 256 * m;
        if (cc < NCLS) { v[m] = __expf(v[m] - mx); sum += v[m]; }
    }
    red[tid] = sum; __syncthreads();
    for (int s = 128; s > 0; s >>= 1) {
        if (tid < s) red[tid] += red[tid + s];
        __syncthreads();
    }
    float inv = 1.0f / red[0];
    #pragma unroll
    for (int m = 0; m < 4; ++m) {
        int cc = tid + 256 * m;
        if (cc < NCLS) out[(size_t)b * NCLS + cc] = v[m] * inv;
    }
}

extern "C" void kernel_launch(void* const* d_in, const int* in_sizes, int n_in,
                              void* d_out, int out_size, void* d_ws, size_t ws_size,
                              hipStream_t stream) {
    const float* x   = (const float*)d_in[0];
    const float* Wfx = (const float*)d_in[1];
    const float* Wfh = (const float*)d_in[2];
    const float* bf_ = (const float*)d_in[3];
    const float* Wix = (const float*)d_in[4];
    const float* Wih = (const float*)d_in[5];
    const float* bi_ = (const float*)d_in[6];
    const float* Wox = (const float*)d_in[7];
    const float* Woh = (const float*)d_in[8];
    const float* bo_ = (const float*)d_in[9];
    const float* Wcx = (const float*)d_in[10];
    const float* bc_ = (const float*)d_in[11];
    const float* Wp  = (const float*)d_in[12];
    const float* bp  = (const float*)d_in[13];

    char* ws = (char*)d_ws;
    bf16*  WhPK = (bf16*)(ws + OFF_WHPK);
    bf16*  WxPK = (bf16*)(ws + OFF_WXPK);
    float* bias = (float*)(ws + OFF_BIAS);
    bf16*  hb0  = (bf16*)(ws + OFF_HB0);
    bf16*  hb1  = (bf16*)(ws + OFF_HB1);
    int*   flags= (int*)(ws + OFF_FLAGS);
    float* lg   = (float*)(ws + OFF_LG);
    bf16*  xb   = (bf16*)(ws + OFF_XB);

    init_state<<<(BB * HH + 255) / 256, 256, 0, stream>>>(hb0, flags);
    pack_wh<<<3 * 16 * 16, 256, 0, stream>>>(Wfh, Wih, Woh, WhPK);
    pack_wx<<<4 * 16 * 8, 256, 0, stream>>>(Wfx, Wix, Wox, Wcx, WxPK);
    pack_bias<<<16, 256, 0, stream>>>(bf_, bi_, bo_, bc_, bias);

    const bool big = (ws_size >= (size_t)WS_BIG);
    if (big) {
        conv_x<<<(BB * TT * II) / (8 * 256), 256, 0, stream>>>(x, xb);
        lstm_persist<true><<<NBLK, 256, 65536, stream>>>(x, xb, WhPK, WxPK, bias,
                                                         hb0, hb1, flags);
    } else {
        lstm_persist<false><<<NBLK, 256, 65536, stream>>>(x, xb, WhPK, WxPK, bias,
                                                          hb0, hb1, flags);
    }

    // T=256 even -> final h in hb0
    logits_kernel<<<BB / 8, 256, 0, stream>>>(hb0, Wp, bp, lg);
    softmax_kernel<<<BB, 256, 0, stream>>>(lg, (float*)d_out);
}